// Round 7
// baseline (180.731 us; speedup 1.0000x reference)
//
#include <hip/hip_runtime.h>

#define CIN 16
#define HH 256
#define WW 256
#define HID 128
#define TH 32            // tile rows per block
#define TW 16            // tile cols per block
#define KEFF 144         // 9 taps * 16 channels
#define WS_BYTES (HID * KEFF * 2 + CIN * HID * 2)   // 36864 + 4096 = 40960

typedef short short8b __attribute__((ext_vector_type(8)));
typedef float f32x4 __attribute__((ext_vector_type(4)));

// fp32 -> bf16 round-to-nearest-even (finite inputs)
__device__ __forceinline__ unsigned short f2bf(float f) {
    union { float f; unsigned int u; } v; v.f = f;
    unsigned int u = v.u;
    return (unsigned short)((u + 0x7fffu + ((u >> 16) & 1u)) >> 16);
}

// Pre-kernel: Weff[o][tap][c] = W1[o][c]*d(tap==4) + W1[o][16+c]*Sx + W1[o][32+c]*Sy ; then w2 bf16.
__global__ __launch_bounds__(256) void build_weff(
    const float* __restrict__ w1, const float* __restrict__ w2,
    unsigned short* __restrict__ ws)
{
    const float SX[9] = {-1.f, 0.f, 1.f, -2.f, 0.f, 2.f, -1.f, 0.f, 1.f};
    const float SY[9] = {-1.f, -2.f, -1.f, 0.f, 0.f, 0.f, 1.f, 2.f, 1.f};
    const int idx = blockIdx.x * 256 + threadIdx.x;
    if (idx < HID * KEFF) {
        const int o = idx / KEFF, r = idx % KEFF;
        const int tap = r >> 4, c = r & 15;
        float v = w1[o * 48 + 16 + c] * SX[tap] + w1[o * 48 + 32 + c] * SY[tap];
        if (tap == 4) v += w1[o * 48 + c];
        ws[idx] = f2bf(v);
    } else if (idx < HID * KEFF + CIN * HID) {
        ws[idx] = f2bf(w2[idx - HID * KEFF]);
    }
}

// LDS carve (bytes):
//   xl   : [0, 19584)         [34][18][16] bf16 channel-last, 32 B/pixel
//   hbuf : [19584, 35968)     [2 pairs][2 phases][16 rows][256 B], XOR-swizzled
//   zreg : [35968, 36000)     32 B zeros
#define SM6_XL  0
#define SM6_HB  19584
#define SM6_ZR  35968
#define SM6_TOT 36000

__global__ __launch_bounds__(256, 3) void updatenet_v6(
    const float* __restrict__ x,             // [B,16,256,256]
    const unsigned short* __restrict__ ws,   // bf16 weff[128][144] + w2[16][128]
    float* __restrict__ out)                 // [B,16,256,256]
{
    __shared__ __align__(16) unsigned char smem[SM6_TOT];
    unsigned short* xl   = (unsigned short*)(smem + SM6_XL);
    unsigned short* zreg = (unsigned short*)(smem + SM6_ZR);

    const int b  = blockIdx.z;
    const int i0 = blockIdx.y * TH;
    const int j0 = blockIdx.x * TW;
    const int t  = threadIdx.x;     // 0..255

    // ---- stage x tile (channel-last bf16, zero-pad OOB) ----
    {
        const size_t cs = (size_t)HH * WW;
        for (int pidx = t; pidx < 34 * 18; pidx += 256) {
            const int ri = pidx / 18, rj = pidx % 18;
            const int ii = i0 + ri - 1, jj = j0 + rj - 1;
            const bool ok = (ii >= 0) & (ii < HH) & (jj >= 0) & (jj < WW);
            const float* xp = x + ((size_t)b * CIN * HH + ii) * WW + jj;
            short8b s0, s1;
            #pragma unroll
            for (int c = 0; c < 8; ++c) {
                s0[c] = ok ? (short)f2bf(xp[c * cs]) : (short)0;
                s1[c] = ok ? (short)f2bf(xp[(c + 8) * cs]) : (short)0;
            }
            *(short8b*)(xl + pidx * 16)     = s0;
            *(short8b*)(xl + pidx * 16 + 8) = s1;
        }
        if (t < 2) *(short8b*)(zreg + t * 8) = (short8b)0;
    }

    const int wv   = t >> 6;
    const int lane = t & 63;
    const int p    = wv >> 1;       // pixel half: rows 16p .. 16p+15
    const int q    = wv & 1;        // o half: o in [64q, 64q+64)
    const int g    = lane >> 4;     // k-group 0..3
    const int nn   = lane & 15;     // MFMA row/col-in-tile
    const int gh   = g >> 1, gl = g & 1;

    // ---- A1 fragments RESIDENT: loaded once from ws, pinned so the compiler
    // cannot rematerialize the (invariant) loads inside the s-loop.
    // ks<4: k = 32ks+8g. ks=4: k = 128+8*gl (payload for g=0,1; g>=2 reads in-row
    // data that is multiplied by a zero B fragment — never leaves its row).
    short8b aW1[4][5];
    #pragma unroll
    for (int mt = 0; mt < 4; ++mt) {
        #pragma unroll
        for (int ks = 0; ks < 5; ++ks) {
            const int ak = (ks == 4) ? (128 + 8 * gl) : (32 * ks + 8 * g);
            aW1[mt][ks] = *(const short8b*)(ws + (size_t)(64 * q + 16 * mt + nn) * KEFF + ak);
        }
    }
    short8b aW2[4];
    #pragma unroll
    for (int ks = 0; ks < 4; ++ks)
        aW2[ks] = *(const short8b*)(ws + HID * KEFF + nn * HID + 32 * ks + 8 * g);

    #pragma unroll
    for (int mt = 0; mt < 4; ++mt)
        #pragma unroll
        for (int ks = 0; ks < 5; ++ks)
            asm volatile("" : "+v"(aW1[mt][ks]));
    #pragma unroll
    for (int ks = 0; ks < 4; ++ks)
        asm volatile("" : "+v"(aW2[ks]));

    // per-lane tap byte-offsets into xl: tap = 2ks+gh, (di,dj) = (tap/3, tap%3)
    int off[5];
    #pragma unroll
    for (int ks = 0; ks < 5; ++ks) {
        int tap = 2 * ks + gh;
        if (tap > 8) tap = 8;       // ks=4,gh=1 -> B redirected to zreg
        off[ks] = ((tap / 3) * 18 + (tap % 3)) * 32 + gl * 16;
    }

    unsigned char* hb_pair = smem + SM6_HB + p * 8192;   // 2 phases x 16 x 256 B
    const int xmask = (nn & 7) << 4;                      // hbuf XOR swizzle

    __syncthreads();

    // ---- 16 rows per pair; dbuf phases; alternating layer-2 worker ----
    for (int s = 0; s < 16; ++s) {
        const int row = 16 * p + s;
        const unsigned char* xbase = (const unsigned char*)xl + (row * 18 + nn) * 32;

        // layer-1: h-half[o 64q..][pix row,0..15]
        f32x4 acc[4];
        #pragma unroll
        for (int mt = 0; mt < 4; ++mt) acc[mt] = (f32x4)0.f;

        #pragma unroll
        for (int ks = 0; ks < 5; ++ks) {
            const unsigned char* bp = (ks == 4 && gh) ? (const unsigned char*)(zreg + gl * 8)
                                                      : xbase + off[ks];
            const short8b bfrag = *(const short8b*)bp;
            #pragma unroll
            for (int mt = 0; mt < 4; ++mt)
                acc[mt] = __builtin_amdgcn_mfma_f32_16x16x32_bf16(aW1[mt][ks], bfrag, acc[mt], 0, 0, 0);
        }

        // relu -> bf16 -> shared hbuf phase s&1 (XOR-swizzled rows of 256 B)
        unsigned char* hph = hb_pair + (s & 1) * 4096;
        #pragma unroll
        for (int mt = 0; mt < 4; ++mt) {
            const unsigned int lo = (unsigned int)f2bf(fmaxf(acc[mt][0], 0.f))
                                  | ((unsigned int)f2bf(fmaxf(acc[mt][1], 0.f)) << 16);
            const unsigned int hi = (unsigned int)f2bf(fmaxf(acc[mt][2], 0.f))
                                  | ((unsigned int)f2bf(fmaxf(acc[mt][3], 0.f)) << 16);
            uint2 u; u.x = lo; u.y = hi;
            const int wb = (nn << 8) + ((64 * q + 16 * mt + 4 * g) << 1);
            *(uint2*)(hph + (wb ^ xmask)) = u;
        }

        __syncthreads();   // h(s) visible; also fences phase reuse (s-2 readers done)

        // layer-2 (full K=128) by alternating worker wave; other wave runs ahead
        if (q == (s & 1)) {
            f32x4 a2 = (f32x4)0.f;
            #pragma unroll
            for (int ks2 = 0; ks2 < 4; ++ks2) {
                const int rb = (nn << 8) + ((32 * ks2 + 8 * g) << 1);
                const short8b bh = *(const short8b*)(hph + (rb ^ xmask));
                a2 = __builtin_amdgcn_mfma_f32_16x16x32_bf16(aW2[ks2], bh, a2, 0, 0, 0);
            }
            const int oi = i0 + row, oj = j0 + nn;
            float* op = out + ((size_t)(b * CIN + 4 * g) * HH + oi) * WW + oj;
            #pragma unroll
            for (int r = 0; r < 4; ++r)
                op[(size_t)r * HH * WW] = a2[r];
        }
    }
}

// ---------- fallback (no usable ws): round-4 kernel, weff built in LDS ----------
#define SM_WEFF  0
#define SM_GUARD 36864
#define SM_W2B   36880
#define SM_XL    41232
#define SM_ZREG  60816
#define SM_HALL  60848
#define SM_TOTAL 78256

__global__ __launch_bounds__(256, 2) void updatenet_fallback(
    const float* __restrict__ x, const float* __restrict__ w1f,
    const float* __restrict__ w2f, float* __restrict__ out)
{
    __shared__ __align__(16) unsigned char smem[SM_TOTAL];
    unsigned short* weff = (unsigned short*)(smem + SM_WEFF);
    unsigned short* w2b  = (unsigned short*)(smem + SM_W2B);
    unsigned short* xl   = (unsigned short*)(smem + SM_XL);
    unsigned short* zreg = (unsigned short*)(smem + SM_ZREG);

    const int b  = blockIdx.z;
    const int i0 = blockIdx.y * TH;
    const int j0 = blockIdx.x * TW;
    const int t  = threadIdx.x;

    for (int idx = t; idx < HID * KEFF; idx += 256) {
        const float SX[9] = {-1.f, 0.f, 1.f, -2.f, 0.f, 2.f, -1.f, 0.f, 1.f};
        const float SY[9] = {-1.f, -2.f, -1.f, 0.f, 0.f, 0.f, 1.f, 2.f, 1.f};
        const int o = idx / KEFF, r = idx % KEFF;
        const int tap = r >> 4, cc = r & 15;
        float v = w1f[o * 48 + 16 + cc] * SX[tap] + w1f[o * 48 + 32 + cc] * SY[tap];
        if (tap == 4) v += w1f[o * 48 + cc];
        weff[idx] = f2bf(v);
    }
    for (int idx = t; idx < CIN * HID; idx += 256)
        w2b[(idx >> 7) * 136 + (idx & 127)] = f2bf(w2f[idx]);

    {
        const size_t cs = (size_t)HH * WW;
        for (int pp = t; pp < 34 * 18; pp += 256) {
            const int ri = pp / 18, rj = pp % 18;
            const int ii = i0 + ri - 1, jj = j0 + rj - 1;
            const bool ok = (ii >= 0) & (ii < HH) & (jj >= 0) & (jj < WW);
            const float* xp = x + ((size_t)b * CIN * HH + ii) * WW + jj;
            short8b s0, s1;
            #pragma unroll
            for (int c = 0; c < 8; ++c) {
                s0[c] = ok ? (short)f2bf(xp[c * cs]) : (short)0;
                s1[c] = ok ? (short)f2bf(xp[(c + 8) * cs]) : (short)0;
            }
            *(short8b*)(xl + pp * 16)     = s0;
            *(short8b*)(xl + pp * 16 + 8) = s1;
        }
        if (t < 2) *(short8b*)(zreg + t * 8) = (short8b)0;
        if (t == 2) *(short8b*)(smem + SM_GUARD) = (short8b)0;
    }
    __syncthreads();

    const int w = t >> 6, lane = t & 63;
    const int g = lane >> 4, nn = lane & 15;
    const int gh = g >> 1, gl = g & 1;

    short8b aW1[8][5];
    #pragma unroll
    for (int m = 0; m < 8; ++m)
        #pragma unroll
        for (int ks = 0; ks < 5; ++ks) {
            const int ak = (ks == 4) ? (128 + 8 * gl) : (32 * ks + 8 * g);
            aW1[m][ks] = *(const short8b*)(weff + (16 * m + nn) * KEFF + ak);
        }

    int off[5];
    #pragma unroll
    for (int ks = 0; ks < 5; ++ks) {
        int tap = 2 * ks + gh;
        if (tap > 8) tap = 8;
        off[ks] = ((tap / 3) * 18 + (tap % 3)) * 32 + gl * 16;
    }

    unsigned short* hb = (unsigned short*)(smem + SM_HALL) + w * (16 * 136);

    for (int nt = 0; nt < 8; ++nt) {
        const int i = 8 * w + nt;
        const unsigned char* xbase = (const unsigned char*)xl + (i * 18 + nn) * 32;
        f32x4 acc[8];
        #pragma unroll
        for (int m = 0; m < 8; ++m) acc[m] = (f32x4)0.f;
        #pragma unroll
        for (int ks = 0; ks < 5; ++ks) {
            const unsigned char* bp = (ks == 4 && gh) ? (const unsigned char*)(zreg + gl * 8)
                                                      : xbase + off[ks];
            const short8b bfrag = *(const short8b*)bp;
            #pragma unroll
            for (int m = 0; m < 8; ++m)
                acc[m] = __builtin_amdgcn_mfma_f32_16x16x32_bf16(aW1[m][ks], bfrag, acc[m], 0, 0, 0);
        }
        #pragma unroll
        for (int m = 0; m < 8; ++m) {
            const unsigned int lo = (unsigned int)f2bf(fmaxf(acc[m][0], 0.f))
                                  | ((unsigned int)f2bf(fmaxf(acc[m][1], 0.f)) << 16);
            const unsigned int hi = (unsigned int)f2bf(fmaxf(acc[m][2], 0.f))
                                  | ((unsigned int)f2bf(fmaxf(acc[m][3], 0.f)) << 16);
            uint2 u; u.x = lo; u.y = hi;
            *(uint2*)(hb + nn * 136 + 16 * m + 4 * g) = u;
        }
        asm volatile("s_waitcnt lgkmcnt(0)" ::: "memory");
        f32x4 a2 = (f32x4)0.f;
        #pragma unroll
        for (int ks = 0; ks < 4; ++ks) {
            const short8b aw2 = *(const short8b*)(w2b + nn * 136 + 32 * ks + 8 * g);
            const short8b bh  = *(const short8b*)(hb + nn * 136 + 32 * ks + 8 * g);
            a2 = __builtin_amdgcn_mfma_f32_16x16x32_bf16(aw2, bh, a2, 0, 0, 0);
        }
        const int oi = i0 + i, oj = j0 + nn;
        float* op = out + ((size_t)(b * CIN + 4 * g) * HH + oi) * WW + oj;
        #pragma unroll
        for (int r = 0; r < 4; ++r)
            op[(size_t)r * HH * WW] = a2[r];
    }
}

extern "C" void kernel_launch(void* const* d_in, const int* in_sizes, int n_in,
                              void* d_out, int out_size, void* d_ws, size_t ws_size,
                              hipStream_t stream) {
    const float* x  = (const float*)d_in[0];
    const float* w1 = (const float*)d_in[1];
    const float* w2 = (const float*)d_in[2];
    float* out = (float*)d_out;

    const int Bn = in_sizes[0] / (CIN * HH * WW);   // 32
    dim3 grid(WW / TW, HH / TH, Bn);                // 16 x 8 x 32 = 4096 blocks

    if (ws_size >= (size_t)WS_BYTES) {
        unsigned short* ws = (unsigned short*)d_ws;
        build_weff<<<(HID * KEFF + CIN * HID + 255) / 256, 256, 0, stream>>>(w1, w2, ws);
        updatenet_v6<<<grid, 256, 0, stream>>>(x, ws, out);
    } else {
        updatenet_fallback<<<grid, 256, 0, stream>>>(x, w1, w2, out);
    }
}